// Round 1
// baseline (867.677 us; speedup 1.0000x reference)
//
#include <hip/hip_runtime.h>
#include <hip/hip_bf16.h>

// ---------------------------------------------------------------------------
// TriangularSelfAttention fused kernel (round 1: correctness-first, MFMA).
// One block per batch element (4096 blocks), 512 threads = 8 waves.
// Phases: gather -> QKV proj (MFMA) -> per-head attention (MFMA, transposed
// scores, softmax without max-shift) -> out-proj + residual + LN -> scatter.
// ---------------------------------------------------------------------------

typedef __bf16 bf8 __attribute__((ext_vector_type(8)));
typedef float f32x4 __attribute__((ext_vector_type(4)));
typedef unsigned int u32x4 __attribute__((ext_vector_type(4)));

#define LDS_BYTES 159488

// LDS arena (byte offsets). Regions are time-multiplexed across phases:
//  XT  [192][72] bf16  : gathered x+pos (live until residual)
//  WI  [192][72] bf16  : w_in      (P1) | P-scratch waves 0-3 (P2) | WO/BO/LG/LB (P3)
//  BI  [192]    f32    : b_in
//  QK  [192][136] bf16 : q (cols 0..63, pre-scaled) + k (cols 64..127); o overwrites q-cols in P2
//  VT  [64][200] bf16  : v transposed [dim][key] (P2) | Z f32 [192][64] (P3)
//  PT  4*6400          : P-scratch waves 4-7
#define OFF_XT 0
#define OFF_WI 27648
#define OFF_BI 55296
#define OFF_QK 56064
#define OFF_VT 108288
#define OFF_PT 133888
#define OFF_WO 27648
#define OFF_BO 36864
#define OFF_LG 37120
#define OFF_LB 37376

__device__ __forceinline__ unsigned short f2b(float f) {
  return __builtin_bit_cast(unsigned short, __float2bfloat16(f));
}
__device__ __forceinline__ float b2f(unsigned short u) {
  unsigned int x = (unsigned int)u << 16;
  return __builtin_bit_cast(float, x);
}
__device__ __forceinline__ bf8 ldsb8(const unsigned short* p) {
  u32x4 u = *(const u32x4*)p;
  return __builtin_bit_cast(bf8, u);
}
__device__ __forceinline__ f32x4 mfma16(bf8 a, bf8 b, f32x4 c) {
  return __builtin_amdgcn_mfma_f32_16x16x32_bf16(a, b, c, 0, 0, 0);
}

__global__ void __launch_bounds__(512)
tri_attn_kernel(const float* __restrict__ x, const float* __restrict__ pos,
                const float* __restrict__ w_in, const float* __restrict__ b_in,
                const float* __restrict__ w_out, const float* __restrict__ b_out,
                const float* __restrict__ ln_g, const float* __restrict__ ln_b,
                float* __restrict__ out)
{
  extern __shared__ char lds[];
  unsigned short* XT = (unsigned short*)(lds + OFF_XT);
  unsigned short* WI = (unsigned short*)(lds + OFF_WI);
  float*          BI = (float*)(lds + OFF_BI);
  unsigned short* QK = (unsigned short*)(lds + OFF_QK);
  unsigned short* VT = (unsigned short*)(lds + OFF_VT);

  const int tid  = threadIdx.x;
  const int lane = tid & 63;
  const int wv   = tid >> 6;
  const int q15  = lane & 15;
  const int g    = lane >> 4;
  const int b    = blockIdx.x;

  // ---------------- P0: stage w_in/b_in, gather x + pos_emb ----------------
  for (int idx = tid; idx < 3072; idx += 512) {        // w_in 192*64 f32 as float4
    int e = idx >> 4, c = idx & 15;
    float4 v = ((const float4*)w_in)[idx];
    unsigned short* d = WI + e * 72 + c * 4;
    d[0] = f2b(v.x); d[1] = f2b(v.y); d[2] = f2b(v.z); d[3] = f2b(v.w);
  }
  if (tid < 192) BI[tid] = b_in[tid];
  const float* xb = x + (size_t)b * (361 * 64);
  for (int idx = tid; idx < 3040; idx += 512) {        // 190 rows * 16 float4
    int s = idx >> 4, c = idx & 15;
    int i = 0, base = 0;                               // tri row/col from s
    while (base + (19 - i) <= s) { base += 19 - i; ++i; }
    int f = i * 19 + (i + (s - base));
    float4 v = ((const float4*)(xb + f * 64))[c];
    float4 p = ((const float4*)(pos + s * 64))[c];
    unsigned short* d = XT + s * 72 + c * 4;
    d[0] = f2b(v.x + p.x); d[1] = f2b(v.y + p.y);
    d[2] = f2b(v.z + p.z); d[3] = f2b(v.w + p.w);
  }
  if (tid < 32) {                                      // zero xt pad rows 190,191
    int s = 190 + (tid >> 4), c = (tid & 15) * 4;
    unsigned short* d = XT + s * 72 + c;
    d[0] = 0; d[1] = 0; d[2] = 0; d[3] = 0;
  }
  if (tid < 128) {                                     // zero VT pad keys 190,191
    int dd = tid >> 1, c = 190 + (tid & 1);
    VT[dd * 200 + c] = 0;
  }
  __syncthreads();

  // ---------------- P1: QKV projection, 12x12 tiles of 16x16 ----------------
  const float qscale = 0.35355339059327373f;           // 1/sqrt(hd) folded into q
  for (int T = wv; T < 144; T += 8) {
    int mt = T % 12, nt = T / 12;
    int m0 = mt * 16, n0 = nt * 16;
    float ci = BI[n0 + q15];
    f32x4 acc = {ci, ci, ci, ci};                      // C init = bias (per-col)
    #pragma unroll
    for (int ks = 0; ks < 2; ++ks) {
      bf8 a  = ldsb8(XT + (m0 + q15) * 72 + ks * 32 + g * 8);
      bf8 w8 = ldsb8(WI + (n0 + q15) * 72 + ks * 32 + g * 8);
      acc = mfma16(a, w8, acc);
    }
    int col = n0 + q15;
    #pragma unroll
    for (int r = 0; r < 4; ++r) {                      // D: row=(g*4+r), col=q15 (m89-verified)
      int row = m0 + g * 4 + r;
      float v = acc[r];
      if (col < 64)       QK[row * 136 + col] = f2b(v * qscale);
      else if (col < 128) QK[row * 136 + col] = f2b(v);
      else if (row < 190) VT[(col - 128) * 200 + row] = f2b(v);
    }
  }
  __syncthreads();

  // ---------------- P2: attention, wave = head ----------------
  const int h = wv;
  unsigned short* Psc = (unsigned short*)(lds + ((wv < 4) ? (OFF_WI + wv * 6400)
                                                          : (OFF_PT + (wv - 4) * 6400)));
  u32x4 kf[12];                                        // cache key A-frags across chunks
  #pragma unroll
  for (int kt = 0; kt < 12; ++kt) {
    u32x4 u = {0, 0, 0, 0};
    if (g == 0) u = *(const u32x4*)(QK + (kt * 16 + q15) * 136 + 64 + h * 8);
    kf[kt] = u;
  }
  for (int mc = 0; mc < 12; ++mc) {                    // 16-query chunks
    int m0 = mc * 16;
    u32x4 uq = {0, 0, 0, 0};
    if (g == 0) uq = *(const u32x4*)(QK + (m0 + q15) * 136 + h * 8);
    bf8 bq = __builtin_bit_cast(bf8, uq);
    // scores transposed: T[key][query] = K . Q^T   (lane owns query col q15)
    float p[48];
    #pragma unroll
    for (int kt = 0; kt < 12; ++kt) {
      f32x4 acc = {0.f, 0.f, 0.f, 0.f};
      acc = mfma16(__builtin_bit_cast(bf8, kf[kt]), bq, acc);
      #pragma unroll
      for (int r = 0; r < 4; ++r) p[kt * 4 + r] = acc[r];
    }
    // softmax without max-shift (|s| bounded ~1.2 by construction)
    #pragma unroll
    for (int i2 = 0; i2 < 48; ++i2) p[i2] = __expf(p[i2]);
    if (g == 3) { p[46] = 0.f; p[47] = 0.f; }          // mask pad keys 190,191
    float S = 0.f;
    #pragma unroll
    for (int i2 = 0; i2 < 48; ++i2) S += p[i2];
    S += __shfl_xor(S, 16);
    S += __shfl_xor(S, 32);                            // denom for query q15
    // write P chunk: Psc[q_local][key] bf16, 4-key b64 packs
    #pragma unroll
    for (int kt = 0; kt < 12; ++kt) {
      unsigned long long pk = (unsigned long long)f2b(p[kt * 4 + 0])
        | ((unsigned long long)f2b(p[kt * 4 + 1]) << 16)
        | ((unsigned long long)f2b(p[kt * 4 + 2]) << 32)
        | ((unsigned long long)f2b(p[kt * 4 + 3]) << 48);
      *(unsigned long long*)(Psc + q15 * 200 + kt * 16 + g * 4) = pk;
    }
    // PV: O^T = V^T . P^T
    f32x4 o = {0.f, 0.f, 0.f, 0.f};
    #pragma unroll
    for (int ks = 0; ks < 6; ++ks) {
      u32x4 ua = {0, 0, 0, 0};
      if (q15 < 8) ua = *(const u32x4*)(VT + (h * 8 + q15) * 200 + ks * 32 + g * 8);
      bf8 a  = __builtin_bit_cast(bf8, ua);
      bf8 pb = ldsb8(Psc + q15 * 200 + ks * 32 + g * 8);
      o = mfma16(a, pb, o);
    }
    float inv = 1.f / S;
    if (g < 2) {                                       // rows = head dims 0..7
      int qa = m0 + q15;
      if (qa < 190) {
        #pragma unroll
        for (int r = 0; r < 4; ++r)
          QK[qa * 136 + h * 8 + g * 4 + r] = f2b(o[r] * inv);  // o into q-region
      }
    }
  }
  __syncthreads();

  // ---------------- P3: out-proj + residual ----------------
  unsigned short* WO = (unsigned short*)(lds + OFF_WO);
  float* BO = (float*)(lds + OFF_BO);
  float* LG = (float*)(lds + OFF_LG);
  float* LB = (float*)(lds + OFF_LB);
  float* Z  = (float*)(lds + OFF_VT);                  // [192][64] f32
  for (int idx = tid; idx < 1024; idx += 512) {        // w_out 64*64 f32
    int e = idx >> 4, c = idx & 15;
    float4 v = ((const float4*)w_out)[idx];
    unsigned short* d = WO + e * 72 + c * 4;
    d[0] = f2b(v.x); d[1] = f2b(v.y); d[2] = f2b(v.z); d[3] = f2b(v.w);
  }
  if (tid < 64) { BO[tid] = b_out[tid]; LG[tid] = ln_g[tid]; LB[tid] = ln_b[tid]; }
  __syncthreads();
  for (int T = wv; T < 48; T += 8) {                   // 12 m-tiles x 4 n-tiles
    int mt = T >> 2, nt = T & 3;
    int m0 = mt * 16, n0 = nt * 16;
    float ci = BO[n0 + q15];
    f32x4 acc = {ci, ci, ci, ci};
    #pragma unroll
    for (int ks = 0; ks < 2; ++ks) {
      bf8 a  = ldsb8(QK + (m0 + q15) * 136 + ks * 32 + g * 8);   // o (q-region)
      bf8 w8 = ldsb8(WO + (n0 + q15) * 72  + ks * 32 + g * 8);
      acc = mfma16(a, w8, acc);
    }
    int col = n0 + q15;
    #pragma unroll
    for (int r = 0; r < 4; ++r) {
      int row = m0 + g * 4 + r;
      Z[row * 64 + col] = acc[r] + b2f(XT[row * 72 + col]);      // residual
    }
  }
  __syncthreads();

  // ---------------- P4: LayerNorm + symmetric scatter ----------------
  float gg = LG[lane];
  float bb = LB[lane];
  float* outb = out + (size_t)b * (361 * 64);
  for (int s = wv; s < 190; s += 8) {                  // wave per row, lane = dim
    float zv = Z[s * 64 + lane];
    float sum = zv;
    #pragma unroll
    for (int m = 1; m < 64; m <<= 1) sum += __shfl_xor(sum, m);
    float mu = sum * 0.015625f;
    float dv = zv - mu;
    float s2 = dv * dv;
    #pragma unroll
    for (int m = 1; m < 64; m <<= 1) s2 += __shfl_xor(s2, m);
    float y = dv * rsqrtf(s2 * 0.015625f + 1e-5f) * gg + bb;
    int i = 0, base = 0;
    while (base + (19 - i) <= s) { base += 19 - i; ++i; }
    int j = i + (s - base);
    outb[(i * 19 + j) * 64 + lane] = y;
    outb[(j * 19 + i) * 64 + lane] = y;                // mirror (diag: same value)
  }
}

extern "C" void kernel_launch(void* const* d_in, const int* in_sizes, int n_in,
                              void* d_out, int out_size, void* d_ws, size_t ws_size,
                              hipStream_t stream) {
  const float* x     = (const float*)d_in[0];
  const float* pos   = (const float*)d_in[1];
  const float* w_in  = (const float*)d_in[2];
  const float* b_in  = (const float*)d_in[3];
  const float* w_out = (const float*)d_in[4];
  const float* b_out = (const float*)d_in[5];
  const float* ln_g  = (const float*)d_in[6];
  const float* ln_b  = (const float*)d_in[7];
  float* out = (float*)d_out;
  (void)in_sizes; (void)n_in; (void)out_size; (void)d_ws; (void)ws_size;
  hipFuncSetAttribute((const void*)tri_attn_kernel,
                      hipFuncAttributeMaxDynamicSharedMemorySize, LDS_BYTES);
  tri_attn_kernel<<<4096, 512, LDS_BYTES, stream>>>(x, pos, w_in, b_in, w_out,
                                                    b_out, ln_g, ln_b, out);
}

// Round 2
// 792.870 us; speedup vs baseline: 1.0943x; 1.0943x over previous
//
#include <hip/hip_runtime.h>
#include <hip/hip_bf16.h>

// ---------------------------------------------------------------------------
// TriangularSelfAttention fused kernel (round 2).
// One block per batch element (4096 blocks), 512 threads = 8 waves.
// Round-2 change: __launch_bounds__(512, 2) -> 256-VGPR cap, eliminating the
// scratch spills that dominated round 1 (VGPR_Count was 64 with a ~160-reg
// working set in the attention loop). Plus closed-form triangular indexing.
// ---------------------------------------------------------------------------

typedef __bf16 bf8 __attribute__((ext_vector_type(8)));
typedef float f32x4 __attribute__((ext_vector_type(4)));
typedef unsigned int u32x4 __attribute__((ext_vector_type(4)));

#define LDS_BYTES 159488

// LDS arena (byte offsets). Regions are time-multiplexed across phases:
//  XT  [192][72] bf16  : gathered x+pos (live until residual)
//  WI  [192][72] bf16  : w_in      (P1) | P-scratch waves 0-3 (P2) | WO/BO/LG/LB (P3)
//  BI  [192]    f32    : b_in
//  QK  [192][136] bf16 : q (cols 0..63, pre-scaled) + k (cols 64..127); o overwrites q-cols in P2
//  VT  [64][200] bf16  : v transposed [dim][key] (P2) | Z f32 [192][64] (P3)
//  PT  4*6400          : P-scratch waves 4-7
#define OFF_XT 0
#define OFF_WI 27648
#define OFF_BI 55296
#define OFF_QK 56064
#define OFF_VT 108288
#define OFF_PT 133888
#define OFF_WO 27648
#define OFF_BO 36864
#define OFF_LG 37120
#define OFF_LB 37376

__device__ __forceinline__ unsigned short f2b(float f) {
  return __builtin_bit_cast(unsigned short, __float2bfloat16(f));
}
__device__ __forceinline__ float b2f(unsigned short u) {
  unsigned int x = (unsigned int)u << 16;
  return __builtin_bit_cast(float, x);
}
__device__ __forceinline__ bf8 ldsb8(const unsigned short* p) {
  u32x4 u = *(const u32x4*)p;
  return __builtin_bit_cast(bf8, u);
}
__device__ __forceinline__ f32x4 mfma16(bf8 a, bf8 b, f32x4 c) {
  return __builtin_amdgcn_mfma_f32_16x16x32_bf16(a, b, c, 0, 0, 0);
}
// closed-form triangular row: i s.t. base(i) <= s < base(i+1), base(i)=i*(39-i)/2
__device__ __forceinline__ int tri_row(int s) {
  int i = (int)floorf((39.0f - sqrtf(1521.0f - 8.0f * (float)s)) * 0.5f);
  if (s < i * (39 - i) / 2) --i;
  else if (s >= (i + 1) * (38 - i) / 2) ++i;
  return i;
}

__global__ void __launch_bounds__(512, 2)
tri_attn_kernel(const float* __restrict__ x, const float* __restrict__ pos,
                const float* __restrict__ w_in, const float* __restrict__ b_in,
                const float* __restrict__ w_out, const float* __restrict__ b_out,
                const float* __restrict__ ln_g, const float* __restrict__ ln_b,
                float* __restrict__ out)
{
  extern __shared__ char lds[];
  unsigned short* XT = (unsigned short*)(lds + OFF_XT);
  unsigned short* WI = (unsigned short*)(lds + OFF_WI);
  float*          BI = (float*)(lds + OFF_BI);
  unsigned short* QK = (unsigned short*)(lds + OFF_QK);
  unsigned short* VT = (unsigned short*)(lds + OFF_VT);

  const int tid  = threadIdx.x;
  const int lane = tid & 63;
  const int wv   = tid >> 6;
  const int q15  = lane & 15;
  const int g    = lane >> 4;
  const int b    = blockIdx.x;

  // ---------------- P0: stage w_in/b_in, gather x + pos_emb ----------------
  for (int idx = tid; idx < 3072; idx += 512) {        // w_in 192*64 f32 as float4
    int e = idx >> 4, c = idx & 15;
    float4 v = ((const float4*)w_in)[idx];
    unsigned short* d = WI + e * 72 + c * 4;
    d[0] = f2b(v.x); d[1] = f2b(v.y); d[2] = f2b(v.z); d[3] = f2b(v.w);
  }
  if (tid < 192) BI[tid] = b_in[tid];
  const float* xb = x + (size_t)b * (361 * 64);
  for (int idx = tid; idx < 3040; idx += 512) {        // 190 rows * 16 float4
    int s = idx >> 4, c = idx & 15;
    int i = tri_row(s);
    int f = i * 19 + i + (s - i * (39 - i) / 2);
    float4 v = ((const float4*)(xb + f * 64))[c];
    float4 p = ((const float4*)(pos + s * 64))[c];
    unsigned short* d = XT + s * 72 + c * 4;
    d[0] = f2b(v.x + p.x); d[1] = f2b(v.y + p.y);
    d[2] = f2b(v.z + p.z); d[3] = f2b(v.w + p.w);
  }
  if (tid < 32) {                                      // zero xt pad rows 190,191
    int s = 190 + (tid >> 4), c = (tid & 15) * 4;
    unsigned short* d = XT + s * 72 + c;
    d[0] = 0; d[1] = 0; d[2] = 0; d[3] = 0;
  }
  if (tid < 128) {                                     // zero VT pad keys 190,191
    int dd = tid >> 1, c = 190 + (tid & 1);
    VT[dd * 200 + c] = 0;
  }
  __syncthreads();

  // ---------------- P1: QKV projection, 12x12 tiles of 16x16 ----------------
  const float qscale = 0.35355339059327373f;           // 1/sqrt(hd) folded into q
  for (int T = wv; T < 144; T += 8) {
    int mt = T % 12, nt = T / 12;
    int m0 = mt * 16, n0 = nt * 16;
    float ci = BI[n0 + q15];
    f32x4 acc = {ci, ci, ci, ci};                      // C init = bias (per-col)
    #pragma unroll
    for (int ks = 0; ks < 2; ++ks) {
      bf8 a  = ldsb8(XT + (m0 + q15) * 72 + ks * 32 + g * 8);
      bf8 w8 = ldsb8(WI + (n0 + q15) * 72 + ks * 32 + g * 8);
      acc = mfma16(a, w8, acc);
    }
    int col = n0 + q15;
    #pragma unroll
    for (int r = 0; r < 4; ++r) {                      // D: row=(g*4+r), col=q15 (m89-verified)
      int row = m0 + g * 4 + r;
      float v = acc[r];
      if (col < 64)       QK[row * 136 + col] = f2b(v * qscale);
      else if (col < 128) QK[row * 136 + col] = f2b(v);
      else if (row < 190) VT[(col - 128) * 200 + row] = f2b(v);
    }
  }
  __syncthreads();

  // ---------------- P2: attention, wave = head ----------------
  const int h = wv;
  unsigned short* Psc = (unsigned short*)(lds + ((wv < 4) ? (OFF_WI + wv * 6400)
                                                          : (OFF_PT + (wv - 4) * 6400)));
  u32x4 kf[12];                                        // cache key A-frags across chunks
  #pragma unroll
  for (int kt = 0; kt < 12; ++kt) {
    u32x4 u = {0, 0, 0, 0};
    if (g == 0) u = *(const u32x4*)(QK + (kt * 16 + q15) * 136 + 64 + h * 8);
    kf[kt] = u;
  }
  for (int mc = 0; mc < 12; ++mc) {                    // 16-query chunks
    int m0 = mc * 16;
    u32x4 uq = {0, 0, 0, 0};
    if (g == 0) uq = *(const u32x4*)(QK + (m0 + q15) * 136 + h * 8);
    bf8 bq = __builtin_bit_cast(bf8, uq);
    // scores transposed: T[key][query] = K . Q^T   (lane owns query col q15)
    float p[48];
    #pragma unroll
    for (int kt = 0; kt < 12; ++kt) {
      f32x4 acc = {0.f, 0.f, 0.f, 0.f};
      acc = mfma16(__builtin_bit_cast(bf8, kf[kt]), bq, acc);
      #pragma unroll
      for (int r = 0; r < 4; ++r) p[kt * 4 + r] = acc[r];
    }
    // softmax without max-shift (|s| bounded ~1.2 by construction)
    #pragma unroll
    for (int i2 = 0; i2 < 48; ++i2) p[i2] = __expf(p[i2]);
    if (g == 3) { p[46] = 0.f; p[47] = 0.f; }          // mask pad keys 190,191
    float S = 0.f;
    #pragma unroll
    for (int i2 = 0; i2 < 48; ++i2) S += p[i2];
    S += __shfl_xor(S, 16);
    S += __shfl_xor(S, 32);                            // denom for query q15
    // write P chunk: Psc[q_local][key] bf16, 4-key b64 packs
    #pragma unroll
    for (int kt = 0; kt < 12; ++kt) {
      unsigned long long pk = (unsigned long long)f2b(p[kt * 4 + 0])
        | ((unsigned long long)f2b(p[kt * 4 + 1]) << 16)
        | ((unsigned long long)f2b(p[kt * 4 + 2]) << 32)
        | ((unsigned long long)f2b(p[kt * 4 + 3]) << 48);
      *(unsigned long long*)(Psc + q15 * 200 + kt * 16 + g * 4) = pk;
    }
    // PV: O^T = V^T . P^T
    f32x4 o = {0.f, 0.f, 0.f, 0.f};
    #pragma unroll
    for (int ks = 0; ks < 6; ++ks) {
      u32x4 ua = {0, 0, 0, 0};
      if (q15 < 8) ua = *(const u32x4*)(VT + (h * 8 + q15) * 200 + ks * 32 + g * 8);
      bf8 a  = __builtin_bit_cast(bf8, ua);
      bf8 pb = ldsb8(Psc + q15 * 200 + ks * 32 + g * 8);
      o = mfma16(a, pb, o);
    }
    float inv = 1.f / S;
    if (g < 2) {                                       // rows = head dims 0..7
      int qa = m0 + q15;
      if (qa < 190) {
        #pragma unroll
        for (int r = 0; r < 4; ++r)
          QK[qa * 136 + h * 8 + g * 4 + r] = f2b(o[r] * inv);  // o into q-region
      }
    }
  }
  __syncthreads();

  // ---------------- P3: out-proj + residual ----------------
  unsigned short* WO = (unsigned short*)(lds + OFF_WO);
  float* BO = (float*)(lds + OFF_BO);
  float* LG = (float*)(lds + OFF_LG);
  float* LB = (float*)(lds + OFF_LB);
  float* Z  = (float*)(lds + OFF_VT);                  // [192][64] f32
  for (int idx = tid; idx < 1024; idx += 512) {        // w_out 64*64 f32
    int e = idx >> 4, c = idx & 15;
    float4 v = ((const float4*)w_out)[idx];
    unsigned short* d = WO + e * 72 + c * 4;
    d[0] = f2b(v.x); d[1] = f2b(v.y); d[2] = f2b(v.z); d[3] = f2b(v.w);
  }
  if (tid < 64) { BO[tid] = b_out[tid]; LG[tid] = ln_g[tid]; LB[tid] = ln_b[tid]; }
  __syncthreads();
  for (int T = wv; T < 48; T += 8) {                   // 12 m-tiles x 4 n-tiles
    int mt = T >> 2, nt = T & 3;
    int m0 = mt * 16, n0 = nt * 16;
    float ci = BO[n0 + q15];
    f32x4 acc = {ci, ci, ci, ci};
    #pragma unroll
    for (int ks = 0; ks < 2; ++ks) {
      bf8 a  = ldsb8(QK + (m0 + q15) * 136 + ks * 32 + g * 8);   // o (q-region)
      bf8 w8 = ldsb8(WO + (n0 + q15) * 72  + ks * 32 + g * 8);
      acc = mfma16(a, w8, acc);
    }
    int col = n0 + q15;
    #pragma unroll
    for (int r = 0; r < 4; ++r) {
      int row = m0 + g * 4 + r;
      Z[row * 64 + col] = acc[r] + b2f(XT[row * 72 + col]);      // residual
    }
  }
  __syncthreads();

  // ---------------- P4: LayerNorm + symmetric scatter ----------------
  float gg = LG[lane];
  float bb = LB[lane];
  float* outb = out + (size_t)b * (361 * 64);
  for (int s = wv; s < 190; s += 8) {                  // wave per row, lane = dim
    float zv = Z[s * 64 + lane];
    float sum = zv;
    #pragma unroll
    for (int m = 1; m < 64; m <<= 1) sum += __shfl_xor(sum, m);
    float mu = sum * 0.015625f;
    float dv = zv - mu;
    float s2 = dv * dv;
    #pragma unroll
    for (int m = 1; m < 64; m <<= 1) s2 += __shfl_xor(s2, m);
    float y = dv * rsqrtf(s2 * 0.015625f + 1e-5f) * gg + bb;
    int i = tri_row(s);
    int j = i + (s - i * (39 - i) / 2);
    outb[(i * 19 + j) * 64 + lane] = y;
    outb[(j * 19 + i) * 64 + lane] = y;                // mirror (diag: same value)
  }
}

extern "C" void kernel_launch(void* const* d_in, const int* in_sizes, int n_in,
                              void* d_out, int out_size, void* d_ws, size_t ws_size,
                              hipStream_t stream) {
  const float* x     = (const float*)d_in[0];
  const float* pos   = (const float*)d_in[1];
  const float* w_in  = (const float*)d_in[2];
  const float* b_in  = (const float*)d_in[3];
  const float* w_out = (const float*)d_in[4];
  const float* b_out = (const float*)d_in[5];
  const float* ln_g  = (const float*)d_in[6];
  const float* ln_b  = (const float*)d_in[7];
  float* out = (float*)d_out;
  (void)in_sizes; (void)n_in; (void)out_size; (void)d_ws; (void)ws_size;
  hipFuncSetAttribute((const void*)tri_attn_kernel,
                      hipFuncAttributeMaxDynamicSharedMemorySize, LDS_BYTES);
  tri_attn_kernel<<<4096, 512, LDS_BYTES, stream>>>(x, pos, w_in, b_in, w_out,
                                                    b_out, ln_g, ln_b, out);
}

// Round 3
// 581.263 us; speedup vs baseline: 1.4927x; 1.3640x over previous
//
#include <hip/hip_runtime.h>
#include <hip/hip_bf16.h>

// ---------------------------------------------------------------------------
// TriangularSelfAttention fused kernel (round 3: 2 blocks/CU).
// One block per batch (4096 blocks), 512 threads = 8 waves, LDS = 79.8 KB.
// Q,K computed transposed and kept in registers; P never leaves registers
// (half-filled-k32 MFMA slot trick); O through LDS; residual in-place in XT.
// ---------------------------------------------------------------------------

typedef __bf16 bf8 __attribute__((ext_vector_type(8)));
typedef float f32x4 __attribute__((ext_vector_type(4)));
typedef unsigned int u32x4 __attribute__((ext_vector_type(4)));
typedef unsigned int u32x2 __attribute__((ext_vector_type(2)));

#define LDS_BYTES 79808
#define OFF_XT 0
#define OFF_O  27360
#define OFF_VT 54720
#define XS 72     // XT row stride (elements)
#define OS 72     // O  row stride
#define VS 196    // VT row stride

__device__ __forceinline__ unsigned short f2b(float f) {
  return __builtin_bit_cast(unsigned short, __float2bfloat16(f));
}
__device__ __forceinline__ float b2f(unsigned short u) {
  unsigned int x = (unsigned int)u << 16;
  return __builtin_bit_cast(float, x);
}
__device__ __forceinline__ unsigned int pk(float lo, float hi) {
  return (unsigned int)f2b(lo) | ((unsigned int)f2b(hi) << 16);
}
__device__ __forceinline__ bf8 ldsb8(const unsigned short* p) {
  u32x4 u = *(const u32x4*)p;
  return __builtin_bit_cast(bf8, u);
}
__device__ __forceinline__ bf8 as_bf8(u32x4 u) { return __builtin_bit_cast(bf8, u); }
__device__ __forceinline__ f32x4 mfma16(bf8 a, bf8 b, f32x4 c) {
  return __builtin_amdgcn_mfma_f32_16x16x32_bf16(a, b, c, 0, 0, 0);
}
__device__ __forceinline__ bf8 load_w8(const float* p) {   // 8 consecutive f32 -> bf8
  float4 a = ((const float4*)p)[0];
  float4 b = ((const float4*)p)[1];
  u32x4 u = { pk(a.x, a.y), pk(a.z, a.w), pk(b.x, b.y), pk(b.z, b.w) };
  return __builtin_bit_cast(bf8, u);
}
// triangular row index: i s.t. base(i) <= s < base(i+1), base(i)=i*(39-i)/2
__device__ __forceinline__ int tri_row(int s) {
  int i = (int)floorf((39.0f - sqrtf(1521.0f - 8.0f * (float)s)) * 0.5f);
  if (s < i * (39 - i) / 2) --i;
  else if (s >= (i + 1) * (38 - i) / 2) ++i;
  return i;
}

__global__ void __launch_bounds__(512, 4)
tri_attn_kernel(const float* __restrict__ x, const float* __restrict__ pos,
                const float* __restrict__ w_in, const float* __restrict__ b_in,
                const float* __restrict__ w_out, const float* __restrict__ b_out,
                const float* __restrict__ ln_g, const float* __restrict__ ln_b,
                float* __restrict__ out)
{
  extern __shared__ char lds[];
  unsigned short* XT = (unsigned short*)(lds + OFF_XT);   // [190][72] x+pos; later Z
  unsigned short* OB = (unsigned short*)(lds + OFF_O);    // [190][72] attention out
  unsigned short* VT = (unsigned short*)(lds + OFF_VT);   // [64][196] V transposed

  const int tid  = threadIdx.x;
  const int lane = tid & 63;
  const int wv   = tid >> 6;      // wave = head
  const int q15  = lane & 15;
  const int g    = lane >> 4;
  const int b    = blockIdx.x;
  const float qscale = 0.35355339059327373f;   // 1/sqrt(8)

  // ---------------- P0: gather x + pos_emb -> XT (bf16) ----------------
  const float* xb = x + (size_t)b * (361 * 64);
  for (int idx = tid; idx < 3040; idx += 512) {            // 190 rows * 16 float4
    int s = idx >> 4, c = idx & 15;
    int i = tri_row(s);
    int j = i + s - i * (39 - i) / 2;
    float4 v = ((const float4*)(xb + (i * 19 + j) * 64))[c];
    float4 p = ((const float4*)(pos + s * 64))[c];
    u32x2 wd = { pk(v.x + p.x, v.y + p.y), pk(v.z + p.z, v.w + p.w) };
    *(u32x2*)(XT + s * XS + c * 4) = wd;
  }
  if (tid < 64) *(unsigned int*)(VT + tid * VS + 190) = 0u;  // zero VT keys 190,191
  __syncthreads();

  // ---------------- P1: projections ----------------
  const int t  = wv >> 1;        // head-pair row-tile (dims 16t..16t+15)
  const int hh = wv & 1;         // which half of the pair is my head
  const int nt = wv & 3;         // V/out-proj n-tile
  const int mtb = wv >> 2;       // V/out-proj m-tile base (0 or 1)

  // Q^T = W_q . X^T  (C: col=query, row=q-dim). Kept in registers (packed bf16).
  bf8 wq0 = load_w8(w_in + (t * 16 + q15) * 64 + g * 8);
  bf8 wq1 = load_w8(w_in + (t * 16 + q15) * 64 + 32 + g * 8);
  float bq0 = b_in[t * 16 + g * 4 + 0], bq1 = b_in[t * 16 + g * 4 + 1];
  float bq2 = b_in[t * 16 + g * 4 + 2], bq3 = b_in[t * 16 + g * 4 + 3];
  unsigned int Qpk[12][2];
  #pragma unroll
  for (int mc = 0; mc < 12; ++mc) {
    f32x4 acc = {0.f, 0.f, 0.f, 0.f};
    acc = mfma16(wq0, ldsb8(XT + (mc * 16 + q15) * XS + g * 8), acc);
    acc = mfma16(wq1, ldsb8(XT + (mc * 16 + q15) * XS + 32 + g * 8), acc);
    bool keep = ((g >> 1) == hh);              // zero the other head's dims
    float v0 = keep ? (acc[0] + bq0) * qscale : 0.f;
    float v1 = keep ? (acc[1] + bq1) * qscale : 0.f;
    float v2 = keep ? (acc[2] + bq2) * qscale : 0.f;
    float v3 = keep ? (acc[3] + bq3) * qscale : 0.f;
    Qpk[mc][0] = pk(v0, v1); Qpk[mc][1] = pk(v2, v3);
  }

  // K^T = W_k . X^T  (C: col=key, row=k-dim). Kept in registers.
  bf8 wk0 = load_w8(w_in + (64 + t * 16 + q15) * 64 + g * 8);
  bf8 wk1 = load_w8(w_in + (64 + t * 16 + q15) * 64 + 32 + g * 8);
  float bk0 = b_in[64 + t * 16 + g * 4 + 0], bk1 = b_in[64 + t * 16 + g * 4 + 1];
  float bk2 = b_in[64 + t * 16 + g * 4 + 2], bk3 = b_in[64 + t * 16 + g * 4 + 3];
  unsigned int Kpk[12][2];
  #pragma unroll
  for (int kt = 0; kt < 12; ++kt) {
    f32x4 acc = {0.f, 0.f, 0.f, 0.f};
    acc = mfma16(wk0, ldsb8(XT + (kt * 16 + q15) * XS + g * 8), acc);
    acc = mfma16(wk1, ldsb8(XT + (kt * 16 + q15) * XS + 32 + g * 8), acc);
    Kpk[kt][0] = pk(acc[0] + bk0, acc[1] + bk1);
    Kpk[kt][1] = pk(acc[2] + bk2, acc[3] + bk3);
  }

  // V = X . W_v^T (normal orientation; C: col=v-dim, row=key) -> VT[dim][key]
  {
    bf8 wv0 = load_w8(w_in + (128 + nt * 16 + q15) * 64 + g * 8);
    bf8 wv1 = load_w8(w_in + (128 + nt * 16 + q15) * 64 + 32 + g * 8);
    float bv = b_in[128 + nt * 16 + q15];
    #pragma unroll
    for (int m6 = 0; m6 < 6; ++m6) {
      int mt = mtb + 2 * m6;
      f32x4 acc = {bv, bv, bv, bv};
      acc = mfma16(ldsb8(XT + (mt * 16 + q15) * XS + g * 8), wv0, acc);
      acc = mfma16(ldsb8(XT + (mt * 16 + q15) * XS + 32 + g * 8), wv1, acc);
      unsigned int w0 = pk(acc[0], acc[1]), w1 = pk(acc[2], acc[3]);
      unsigned short* dst = VT + (nt * 16 + q15) * VS + mt * 16 + g * 4;
      if (mt == 11 && g == 3) {            // keys 188,189 only (190,191 stay 0)
        *(unsigned int*)dst = w0;
      } else {
        u32x2 wd = {w0, w1};
        *(u32x2*)dst = wd;
      }
    }
  }
  __syncthreads();

  // ---------------- P2: attention (all in registers, O -> LDS) ----------------
  const int h = wv;
  u32x2 va[12];                      // V^T fragments: dim h*8+(q15&7), keys kt*16+g*4..+3
  #pragma unroll
  for (int kt = 0; kt < 12; ++kt)
    va[kt] = *(const u32x2*)(VT + (h * 8 + (q15 & 7)) * VS + kt * 16 + g * 4);

  #pragma unroll
  for (int mc = 0; mc < 12; ++mc) {
    u32x4 qb = {Qpk[mc][0], Qpk[mc][1], 0u, 0u};
    f32x4 o = {0.f, 0.f, 0.f, 0.f};
    float S = 0.f;
    #pragma unroll
    for (int kt = 0; kt < 12; ++kt) {
      u32x4 ka = {Kpk[kt][0], Kpk[kt][1], 0u, 0u};
      f32x4 sc = mfma16(as_bf8(ka), as_bf8(qb), f32x4{0.f, 0.f, 0.f, 0.f});
      float p0 = __expf(sc[0]);
      float p1 = __expf(sc[1]);
      float p2 = __expf(sc[2]);
      float p3 = __expf(sc[3]);
      if (kt == 11) {                      // mask pad keys 190,191 (also kills Inf/NaN)
        bool mk = (g == 3);
        p2 = mk ? 0.f : p2;
        p3 = mk ? 0.f : p3;
      }
      S += (p0 + p1) + (p2 + p3);
      u32x4 pb = {pk(p0, p1), pk(p2, p3), 0u, 0u};
      u32x4 aa = {va[kt].x, va[kt].y, 0u, 0u};
      o = mfma16(as_bf8(aa), as_bf8(pb), o);
    }
    S += __shfl_xor(S, 16);
    S += __shfl_xor(S, 32);
    float inv = __builtin_amdgcn_rcpf(S);
    int qa = mc * 16 + q15;
    if (g < 2 && qa < 190) {
      u32x2 wd = { pk(o[0] * inv, o[1] * inv), pk(o[2] * inv, o[3] * inv) };
      *(u32x2*)(OB + qa * OS + h * 8 + g * 4) = wd;
    }
  }
  __syncthreads();

  // ---------------- P3: out-proj + residual (Z in-place into XT) ----------------
  {
    bf8 wo0 = load_w8(w_out + (nt * 16 + q15) * 64 + g * 8);
    bf8 wo1 = load_w8(w_out + (nt * 16 + q15) * 64 + 32 + g * 8);
    float bo = b_out[nt * 16 + q15];
    #pragma unroll
    for (int m6 = 0; m6 < 6; ++m6) {
      int mt = mtb + 2 * m6;
      f32x4 acc = {bo, bo, bo, bo};
      acc = mfma16(ldsb8(OB + (mt * 16 + q15) * OS + g * 8), wo0, acc);
      acc = mfma16(ldsb8(OB + (mt * 16 + q15) * OS + 32 + g * 8), wo1, acc);
      #pragma unroll
      for (int r = 0; r < 4; ++r) {
        int row = mt * 16 + g * 4 + r;
        if (row < 190) {
          int col = nt * 16 + q15;
          float z = acc[r] + b2f(XT[row * XS + col]);
          XT[row * XS + col] = f2b(z);
        }
      }
    }
  }
  __syncthreads();

  // ---------------- P4: LayerNorm + symmetric scatter ----------------
  float gg = ln_g[lane];
  float bb = ln_b[lane];
  float* outb = out + (size_t)b * (361 * 64);
  for (int s = wv; s < 190; s += 8) {
    float zv = b2f(XT[s * XS + lane]);
    float sum = zv;
    #pragma unroll
    for (int m = 1; m < 64; m <<= 1) sum += __shfl_xor(sum, m);
    float mu = sum * 0.015625f;
    float dv = zv - mu;
    float s2 = dv * dv;
    #pragma unroll
    for (int m = 1; m < 64; m <<= 1) s2 += __shfl_xor(s2, m);
    float y = dv * rsqrtf(s2 * 0.015625f + 1e-5f) * gg + bb;
    int i = tri_row(s);
    int j = i + s - i * (39 - i) / 2;
    outb[(i * 19 + j) * 64 + lane] = y;
    outb[(j * 19 + i) * 64 + lane] = y;     // mirror (diagonal rewritten, same value)
  }
}

extern "C" void kernel_launch(void* const* d_in, const int* in_sizes, int n_in,
                              void* d_out, int out_size, void* d_ws, size_t ws_size,
                              hipStream_t stream) {
  const float* x     = (const float*)d_in[0];
  const float* pos   = (const float*)d_in[1];
  const float* w_in  = (const float*)d_in[2];
  const float* b_in  = (const float*)d_in[3];
  const float* w_out = (const float*)d_in[4];
  const float* b_out = (const float*)d_in[5];
  const float* ln_g  = (const float*)d_in[6];
  const float* ln_b  = (const float*)d_in[7];
  float* out = (float*)d_out;
  (void)in_sizes; (void)n_in; (void)out_size; (void)d_ws; (void)ws_size;
  hipFuncSetAttribute((const void*)tri_attn_kernel,
                      hipFuncAttributeMaxDynamicSharedMemorySize, LDS_BYTES);
  tri_attn_kernel<<<4096, 512, LDS_BYTES, stream>>>(x, pos, w_in, b_in, w_out,
                                                    b_out, ln_g, ln_b, out);
}

// Round 4
// 561.569 us; speedup vs baseline: 1.5451x; 1.0351x over previous
//
#include <hip/hip_runtime.h>
#include <hip/hip_bf16.h>

// ---------------------------------------------------------------------------
// TriangularSelfAttention fused kernel (round 4).
// One block per batch (4096 blocks), 512 threads = 8 waves, LDS = 79.8 KB
// (2 blocks/CU). Round-4 change: amdgpu_waves_per_eu(4,4) pins the register
// allocator to the LDS-limited occupancy (4 waves/EU -> 128-VGPR budget),
// eliminating the scratch spills of round 3 (WRITE_SIZE was 1.06 GB vs the
// 378 MB output). Also: exp -> exp2 with log2(e) folded into the Q scale.
// ---------------------------------------------------------------------------

typedef __bf16 bf8 __attribute__((ext_vector_type(8)));
typedef float f32x4 __attribute__((ext_vector_type(4)));
typedef unsigned int u32x4 __attribute__((ext_vector_type(4)));
typedef unsigned int u32x2 __attribute__((ext_vector_type(2)));

#define LDS_BYTES 79808
#define OFF_XT 0
#define OFF_O  27360
#define OFF_VT 54720
#define XS 72     // XT row stride (elements)
#define OS 72     // O  row stride
#define VS 196    // VT row stride

__device__ __forceinline__ unsigned short f2b(float f) {
  return __builtin_bit_cast(unsigned short, __float2bfloat16(f));
}
__device__ __forceinline__ float b2f(unsigned short u) {
  unsigned int x = (unsigned int)u << 16;
  return __builtin_bit_cast(float, x);
}
__device__ __forceinline__ unsigned int pk(float lo, float hi) {
  return (unsigned int)f2b(lo) | ((unsigned int)f2b(hi) << 16);
}
__device__ __forceinline__ bf8 ldsb8(const unsigned short* p) {
  u32x4 u = *(const u32x4*)p;
  return __builtin_bit_cast(bf8, u);
}
__device__ __forceinline__ bf8 as_bf8(u32x4 u) { return __builtin_bit_cast(bf8, u); }
__device__ __forceinline__ f32x4 mfma16(bf8 a, bf8 b, f32x4 c) {
  return __builtin_amdgcn_mfma_f32_16x16x32_bf16(a, b, c, 0, 0, 0);
}
__device__ __forceinline__ bf8 load_w8(const float* p) {   // 8 consecutive f32 -> bf8
  float4 a = ((const float4*)p)[0];
  float4 b = ((const float4*)p)[1];
  u32x4 u = { pk(a.x, a.y), pk(a.z, a.w), pk(b.x, b.y), pk(b.z, b.w) };
  return __builtin_bit_cast(bf8, u);
}
// triangular row index: i s.t. base(i) <= s < base(i+1), base(i)=i*(39-i)/2
__device__ __forceinline__ int tri_row(int s) {
  int i = (int)floorf((39.0f - sqrtf(1521.0f - 8.0f * (float)s)) * 0.5f);
  if (s < i * (39 - i) / 2) --i;
  else if (s >= (i + 1) * (38 - i) / 2) ++i;
  return i;
}

__global__ void __launch_bounds__(512)
__attribute__((amdgpu_waves_per_eu(4, 4)))
tri_attn_kernel(const float* __restrict__ x, const float* __restrict__ pos,
                const float* __restrict__ w_in, const float* __restrict__ b_in,
                const float* __restrict__ w_out, const float* __restrict__ b_out,
                const float* __restrict__ ln_g, const float* __restrict__ ln_b,
                float* __restrict__ out)
{
  extern __shared__ char lds[];
  unsigned short* XT = (unsigned short*)(lds + OFF_XT);   // [190][72] x+pos; later Z
  unsigned short* OB = (unsigned short*)(lds + OFF_O);    // [190][72] attention out
  unsigned short* VT = (unsigned short*)(lds + OFF_VT);   // [64][196] V transposed

  const int tid  = threadIdx.x;
  const int lane = tid & 63;
  const int wv   = tid >> 6;      // wave = head
  const int q15  = lane & 15;
  const int g    = lane >> 4;
  const int b    = blockIdx.x;
  // (1/sqrt(8)) * log2(e): softmax via exp2, normalization cancels the base swap
  const float qscale = 0.5100694858979282f;

  // ---------------- P0: gather x + pos_emb -> XT (bf16) ----------------
  const float* xb = x + (size_t)b * (361 * 64);
  for (int idx = tid; idx < 3040; idx += 512) {            // 190 rows * 16 float4
    int s = idx >> 4, c = idx & 15;
    int i = tri_row(s);
    int j = i + s - i * (39 - i) / 2;
    float4 v = ((const float4*)(xb + (i * 19 + j) * 64))[c];
    float4 p = ((const float4*)(pos + s * 64))[c];
    u32x2 wd = { pk(v.x + p.x, v.y + p.y), pk(v.z + p.z, v.w + p.w) };
    *(u32x2*)(XT + s * XS + c * 4) = wd;
  }
  if (tid < 64) *(unsigned int*)(VT + tid * VS + 190) = 0u;  // zero VT keys 190,191
  __syncthreads();

  // ---------------- P1: projections ----------------
  const int t  = wv >> 1;        // head-pair row-tile (dims 16t..16t+15)
  const int hh = wv & 1;         // which half of the pair is my head
  const int nt = wv & 3;         // V/out-proj n-tile
  const int mtb = wv >> 2;       // V/out-proj m-tile base (0 or 1)

  // Q^T = W_q . X^T  (C: col=query, row=q-dim). Kept in registers (packed bf16).
  bf8 wq0 = load_w8(w_in + (t * 16 + q15) * 64 + g * 8);
  bf8 wq1 = load_w8(w_in + (t * 16 + q15) * 64 + 32 + g * 8);
  float bq0 = b_in[t * 16 + g * 4 + 0], bq1 = b_in[t * 16 + g * 4 + 1];
  float bq2 = b_in[t * 16 + g * 4 + 2], bq3 = b_in[t * 16 + g * 4 + 3];
  unsigned int Qpk[12][2];
  #pragma unroll
  for (int mc = 0; mc < 12; ++mc) {
    f32x4 acc = {0.f, 0.f, 0.f, 0.f};
    acc = mfma16(wq0, ldsb8(XT + (mc * 16 + q15) * XS + g * 8), acc);
    acc = mfma16(wq1, ldsb8(XT + (mc * 16 + q15) * XS + 32 + g * 8), acc);
    bool keep = ((g >> 1) == hh);              // zero the other head's dims
    float v0 = keep ? (acc[0] + bq0) * qscale : 0.f;
    float v1 = keep ? (acc[1] + bq1) * qscale : 0.f;
    float v2 = keep ? (acc[2] + bq2) * qscale : 0.f;
    float v3 = keep ? (acc[3] + bq3) * qscale : 0.f;
    Qpk[mc][0] = pk(v0, v1); Qpk[mc][1] = pk(v2, v3);
  }

  // K^T = W_k . X^T  (C: col=key, row=k-dim). Kept in registers.
  bf8 wk0 = load_w8(w_in + (64 + t * 16 + q15) * 64 + g * 8);
  bf8 wk1 = load_w8(w_in + (64 + t * 16 + q15) * 64 + 32 + g * 8);
  float bk0 = b_in[64 + t * 16 + g * 4 + 0], bk1 = b_in[64 + t * 16 + g * 4 + 1];
  float bk2 = b_in[64 + t * 16 + g * 4 + 2], bk3 = b_in[64 + t * 16 + g * 4 + 3];
  unsigned int Kpk[12][2];
  #pragma unroll
  for (int kt = 0; kt < 12; ++kt) {
    f32x4 acc = {0.f, 0.f, 0.f, 0.f};
    acc = mfma16(wk0, ldsb8(XT + (kt * 16 + q15) * XS + g * 8), acc);
    acc = mfma16(wk1, ldsb8(XT + (kt * 16 + q15) * XS + 32 + g * 8), acc);
    Kpk[kt][0] = pk(acc[0] + bk0, acc[1] + bk1);
    Kpk[kt][1] = pk(acc[2] + bk2, acc[3] + bk3);
  }

  // V = X . W_v^T (normal orientation; C: col=v-dim, row=key) -> VT[dim][key]
  {
    bf8 wv0 = load_w8(w_in + (128 + nt * 16 + q15) * 64 + g * 8);
    bf8 wv1 = load_w8(w_in + (128 + nt * 16 + q15) * 64 + 32 + g * 8);
    float bv = b_in[128 + nt * 16 + q15];
    #pragma unroll
    for (int m6 = 0; m6 < 6; ++m6) {
      int mt = mtb + 2 * m6;
      f32x4 acc = {bv, bv, bv, bv};
      acc = mfma16(ldsb8(XT + (mt * 16 + q15) * XS + g * 8), wv0, acc);
      acc = mfma16(ldsb8(XT + (mt * 16 + q15) * XS + 32 + g * 8), wv1, acc);
      unsigned int w0 = pk(acc[0], acc[1]), w1 = pk(acc[2], acc[3]);
      unsigned short* dst = VT + (nt * 16 + q15) * VS + mt * 16 + g * 4;
      if (mt == 11 && g == 3) {            // keys 188,189 only (190,191 stay 0)
        *(unsigned int*)dst = w0;
      } else {
        u32x2 wd = {w0, w1};
        *(u32x2*)dst = wd;
      }
    }
  }
  __syncthreads();

  // ---------------- P2: attention (all in registers, O -> LDS) ----------------
  const int h = wv;
  u32x2 va[12];                      // V^T fragments: dim h*8+(q15&7), keys kt*16+g*4..+3
  #pragma unroll
  for (int kt = 0; kt < 12; ++kt)
    va[kt] = *(const u32x2*)(VT + (h * 8 + (q15 & 7)) * VS + kt * 16 + g * 4);

  #pragma unroll
  for (int mc = 0; mc < 12; ++mc) {
    u32x4 qb = {Qpk[mc][0], Qpk[mc][1], 0u, 0u};
    f32x4 o = {0.f, 0.f, 0.f, 0.f};
    float S = 0.f;
    #pragma unroll
    for (int kt = 0; kt < 12; ++kt) {
      u32x4 ka = {Kpk[kt][0], Kpk[kt][1], 0u, 0u};
      f32x4 sc = mfma16(as_bf8(ka), as_bf8(qb), f32x4{0.f, 0.f, 0.f, 0.f});
      float p0 = __builtin_amdgcn_exp2f(sc[0]);
      float p1 = __builtin_amdgcn_exp2f(sc[1]);
      float p2 = __builtin_amdgcn_exp2f(sc[2]);
      float p3 = __builtin_amdgcn_exp2f(sc[3]);
      if (kt == 11) {                      // mask pad keys 190,191 (also kills Inf/NaN)
        bool mk = (g == 3);
        p2 = mk ? 0.f : p2;
        p3 = mk ? 0.f : p3;
      }
      S += (p0 + p1) + (p2 + p3);
      u32x4 pb = {pk(p0, p1), pk(p2, p3), 0u, 0u};
      u32x4 aa = {va[kt].x, va[kt].y, 0u, 0u};
      o = mfma16(as_bf8(aa), as_bf8(pb), o);
    }
    S += __shfl_xor(S, 16);
    S += __shfl_xor(S, 32);
    float inv = __builtin_amdgcn_rcpf(S);
    int qa = mc * 16 + q15;
    if (g < 2 && qa < 190) {
      u32x2 wd = { pk(o[0] * inv, o[1] * inv), pk(o[2] * inv, o[3] * inv) };
      *(u32x2*)(OB + qa * OS + h * 8 + g * 4) = wd;
    }
  }
  __syncthreads();

  // ---------------- P3: out-proj + residual (Z in-place into XT) ----------------
  {
    bf8 wo0 = load_w8(w_out + (nt * 16 + q15) * 64 + g * 8);
    bf8 wo1 = load_w8(w_out + (nt * 16 + q15) * 64 + 32 + g * 8);
    float bo = b_out[nt * 16 + q15];
    #pragma unroll
    for (int m6 = 0; m6 < 6; ++m6) {
      int mt = mtb + 2 * m6;
      f32x4 acc = {bo, bo, bo, bo};
      acc = mfma16(ldsb8(OB + (mt * 16 + q15) * OS + g * 8), wo0, acc);
      acc = mfma16(ldsb8(OB + (mt * 16 + q15) * OS + 32 + g * 8), wo1, acc);
      #pragma unroll
      for (int r = 0; r < 4; ++r) {
        int row = mt * 16 + g * 4 + r;
        if (row < 190) {
          int col = nt * 16 + q15;
          float z = acc[r] + b2f(XT[row * XS + col]);
          XT[row * XS + col] = f2b(z);
        }
      }
    }
  }
  __syncthreads();

  // ---------------- P4: LayerNorm + symmetric scatter ----------------
  float gg = ln_g[lane];
  float bb = ln_b[lane];
  float* outb = out + (size_t)b * (361 * 64);
  for (int s = wv; s < 190; s += 8) {
    float zv = b2f(XT[s * XS + lane]);
    float sum = zv;
    #pragma unroll
    for (int m = 1; m < 64; m <<= 1) sum += __shfl_xor(sum, m);
    float mu = sum * 0.015625f;
    float dv = zv - mu;
    float s2 = dv * dv;
    #pragma unroll
    for (int m = 1; m < 64; m <<= 1) s2 += __shfl_xor(s2, m);
    float y = dv * rsqrtf(s2 * 0.015625f + 1e-5f) * gg + bb;
    int i = tri_row(s);
    int j = i + s - i * (39 - i) / 2;
    outb[(i * 19 + j) * 64 + lane] = y;
    outb[(j * 19 + i) * 64 + lane] = y;     // mirror (diagonal rewritten, same value)
  }
}

extern "C" void kernel_launch(void* const* d_in, const int* in_sizes, int n_in,
                              void* d_out, int out_size, void* d_ws, size_t ws_size,
                              hipStream_t stream) {
  const float* x     = (const float*)d_in[0];
  const float* pos   = (const float*)d_in[1];
  const float* w_in  = (const float*)d_in[2];
  const float* b_in  = (const float*)d_in[3];
  const float* w_out = (const float*)d_in[4];
  const float* b_out = (const float*)d_in[5];
  const float* ln_g  = (const float*)d_in[6];
  const float* ln_b  = (const float*)d_in[7];
  float* out = (float*)d_out;
  (void)in_sizes; (void)n_in; (void)out_size; (void)d_ws; (void)ws_size;
  hipFuncSetAttribute((const void*)tri_attn_kernel,
                      hipFuncAttributeMaxDynamicSharedMemorySize, LDS_BYTES);
  tri_attn_kernel<<<4096, 512, LDS_BYTES, stream>>>(x, pos, w_in, b_in, w_out,
                                                    b_out, ln_g, ln_b, out);
}